// Round 1
// baseline (538.903 us; speedup 1.0000x reference)
//
#include <hip/hip_runtime.h>

// GNN fused pipeline on MI355X (gfx950), all fp32.
//   z   = BN(l2normalize(x))                      [elementwise, 1 wave/row]
//   deg = histogram(dst)+1 ; dinv = rsqrt(deg)    [atomics]
//   CSR by dst (counting sort: histogram -> scan -> scatter)
//   y   = A_hat * z  (gather over CSR, z is L3-resident)
//   out = leaky( [y|z] @ [W;rs_W] + (b+rs_b) )    [one K=256 fp32 GEMM]
//
// Workspace layout (~110.5 MB): z(51.2M) y(51.2M) cnt dinv rp cursor csr(6.4M) bsum bias2

#define NN 100000
#define DD 128
#define EE 1600000
#define BN_EPS 1e-5f
#define SLOPE 0.01f

__global__ void k_zero(int* __restrict__ p, int n) {
  int i = blockIdx.x * blockDim.x + threadIdx.x;
  if (i < n) p[i] = 0;
}

__global__ void k_bias(const float* __restrict__ b, const float* __restrict__ rb,
                       float* __restrict__ bias2) {
  int i = threadIdx.x;
  if (i < DD) bias2[i] = b[i] + rb[i];
}

// fused row L2-normalize + BatchNorm(eval); one 64-lane wave per row, float2/lane
__global__ void k_norm_bn(const float* __restrict__ x,
                          const float* __restrict__ gamma,
                          const float* __restrict__ beta,
                          const float* __restrict__ mean,
                          const float* __restrict__ var,
                          float* __restrict__ z) {
  int row = blockIdx.x * 4 + (threadIdx.x >> 6);
  int lane = threadIdx.x & 63;
  if (row >= NN) return;
  float2 v = ((const float2*)(x + (size_t)row * DD))[lane];
  float ss = v.x * v.x + v.y * v.y;
  #pragma unroll
  for (int off = 32; off > 0; off >>= 1) ss += __shfl_xor(ss, off);
  float s = 1.0f / fmaxf(sqrtf(ss), 1e-12f);
  int c = lane * 2;
  float g0 = gamma[c]     * rsqrtf(var[c]     + BN_EPS);
  float g1 = gamma[c + 1] * rsqrtf(var[c + 1] + BN_EPS);
  float2 o;
  o.x = (v.x * s - mean[c])     * g0 + beta[c];
  o.y = (v.y * s - mean[c + 1]) * g1 + beta[c + 1];
  ((float2*)(z + (size_t)row * DD))[lane] = o;
}

__global__ void k_count(const int* __restrict__ dst, int* __restrict__ cnt) {
  int e = blockIdx.x * blockDim.x + threadIdx.x;
  if (e < EE) atomicAdd(&cnt[dst[e]], 1);
}

__global__ void k_dinv(const int* __restrict__ cnt, float* __restrict__ dinv) {
  int i = blockIdx.x * blockDim.x + threadIdx.x;
  if (i < NN) dinv[i] = rsqrtf((float)(cnt[i] + 1));  // +1 self-loop
}

// ---- 3-kernel exclusive scan over cnt[N] -> rp[N+1] ----
__global__ void k_scan1(const int* __restrict__ in, int* __restrict__ outp,
                        int* __restrict__ bsum, int n) {
  __shared__ int sh[256];
  int t = threadIdx.x;
  int i = blockIdx.x * 256 + t;
  int v = (i < n) ? in[i] : 0;
  sh[t] = v;
  __syncthreads();
  for (int off = 1; off < 256; off <<= 1) {
    int a = (t >= off) ? sh[t - off] : 0;
    __syncthreads();
    sh[t] += a;
    __syncthreads();
  }
  if (i < n) outp[i] = sh[t] - v;          // exclusive
  if (t == 255) bsum[blockIdx.x] = sh[255];
}

__global__ void k_scan2(int* __restrict__ bsum, int nb) {
  __shared__ int sh[512];
  int t = threadIdx.x;
  int v = (t < nb) ? bsum[t] : 0;
  sh[t] = v;
  __syncthreads();
  for (int off = 1; off < 512; off <<= 1) {
    int a = (t >= off) ? sh[t - off] : 0;
    __syncthreads();
    sh[t] += a;
    __syncthreads();
  }
  if (t < nb) bsum[t] = sh[t] - v;         // exclusive over block sums
}

__global__ void k_scan3(int* __restrict__ rp, const int* __restrict__ bsum, int n) {
  int i = blockIdx.x * 256 + threadIdx.x;
  if (i < n) rp[i] += bsum[blockIdx.x];
  if (i == 0) rp[n] = EE;                  // total
}

__global__ void k_scatter(const int* __restrict__ src, const int* __restrict__ dst,
                          const int* __restrict__ rp, int* __restrict__ cursor,
                          int* __restrict__ csr) {
  int e = blockIdx.x * blockDim.x + threadIdx.x;
  if (e < EE) {
    int d = dst[e];
    int p = atomicAdd(&cursor[d], 1);
    csr[rp[d] + p] = src[e];
  }
}

// y[i] = dinv[i] * ( sum_{j in in-nbrs(i)} dinv[j]*z[j] + dinv[i]*z[i] )
// one wave per node, float2 per lane (512B coalesced row reads), 2x unrolled
__global__ void k_aggregate(const float* __restrict__ z, const int* __restrict__ rp,
                            const int* __restrict__ csr, const float* __restrict__ dinv,
                            float* __restrict__ y) {
  int node = blockIdx.x * 4 + (threadIdx.x >> 6);
  int lane = threadIdx.x & 63;
  if (node >= NN) return;
  int beg = rp[node], end = rp[node + 1];
  float di = dinv[node];
  const float2* zb = (const float2*)z;
  float2 zs = zb[(size_t)node * 64 + lane];
  float2 acc;
  acc.x = di * zs.x;
  acc.y = di * zs.y;
  int k = beg;
  for (; k + 1 < end; k += 2) {
    int j0 = csr[k], j1 = csr[k + 1];
    float d0 = dinv[j0], d1 = dinv[j1];
    float2 a0 = zb[(size_t)j0 * 64 + lane];
    float2 a1 = zb[(size_t)j1 * 64 + lane];
    acc.x += d0 * a0.x + d1 * a1.x;
    acc.y += d0 * a0.y + d1 * a1.y;
  }
  if (k < end) {
    int j0 = csr[k];
    float d0 = dinv[j0];
    float2 a0 = zb[(size_t)j0 * 64 + lane];
    acc.x += d0 * a0.x;
    acc.y += d0 * a0.y;
  }
  acc.x *= di;
  acc.y *= di;
  ((float2*)y)[(size_t)node * 64 + lane] = acc;
}

// out = leaky( [y|z](N x 256) @ [W;rs_W](256 x 128) + bias2 )
// 128x128 block tile, BK=32, 256 threads, 8x8 micro-tile.
// A staged transposed in LDS (stride 132 keeps float4 alignment + conflict-light).
__global__ __launch_bounds__(256) void k_gemm(
    const float* __restrict__ y, const float* __restrict__ z,
    const float* __restrict__ W, const float* __restrict__ rsW,
    const float* __restrict__ bias2, float* __restrict__ out) {
  __shared__ float As[32][132];
  __shared__ float Bs[32][132];
  const int tid = threadIdx.x;
  const int ty = tid >> 4;        // 0..15 -> rows ty*8..ty*8+7
  const int tx = tid & 15;        // 0..15 -> cols {tx*4..+3} and {64+tx*4..+3}
  const int row0 = blockIdx.x * 128;

  float acc[8][8];
  #pragma unroll
  for (int i = 0; i < 8; ++i)
    #pragma unroll
    for (int j = 0; j < 8; ++j) acc[i][j] = 0.f;

  for (int kt = 0; kt < 8; ++kt) {
    const float* Ag = (kt < 4) ? y : z;
    const float* Bg = (kt < 4) ? W : rsW;
    const int kc = (kt & 3) * 32;
    // stage A (128 rows x 32 cols) transposed -> As[k][r]
    #pragma unroll
    for (int i = 0; i < 4; ++i) {
      int lin = tid + i * 256;     // float4 index over [128][8]
      int r = lin >> 3, c4 = lin & 7;
      int gr = row0 + r;
      float4 v = make_float4(0.f, 0.f, 0.f, 0.f);
      if (gr < NN) v = *(const float4*)(Ag + (size_t)gr * DD + kc + c4 * 4);
      int c = c4 * 4;
      As[c + 0][r] = v.x; As[c + 1][r] = v.y; As[c + 2][r] = v.z; As[c + 3][r] = v.w;
    }
    // stage B (32 rows x 128 cols)
    #pragma unroll
    for (int i = 0; i < 4; ++i) {
      int lin = tid + i * 256;     // float4 index over [32][32]
      int r = lin >> 5, c4 = lin & 31;
      float4 v = *(const float4*)(Bg + (size_t)(kc + r) * DD + c4 * 4);
      *(float4*)&Bs[r][c4 * 4] = v;
    }
    __syncthreads();
    #pragma unroll
    for (int k = 0; k < 32; ++k) {
      float4 a0 = *(const float4*)&As[k][ty * 8];
      float4 a1 = *(const float4*)&As[k][ty * 8 + 4];
      float4 b0 = *(const float4*)&Bs[k][tx * 4];
      float4 b1 = *(const float4*)&Bs[k][64 + tx * 4];
      float a[8]  = {a0.x, a0.y, a0.z, a0.w, a1.x, a1.y, a1.z, a1.w};
      float bb[8] = {b0.x, b0.y, b0.z, b0.w, b1.x, b1.y, b1.z, b1.w};
      #pragma unroll
      for (int i = 0; i < 8; ++i)
        #pragma unroll
        for (int j = 0; j < 8; ++j)
          acc[i][j] = fmaf(a[i], bb[j], acc[i][j]);
    }
    __syncthreads();
  }

  float4 bb0 = *(const float4*)(bias2 + tx * 4);
  float4 bb1 = *(const float4*)(bias2 + 64 + tx * 4);
  float bB[8] = {bb0.x, bb0.y, bb0.z, bb0.w, bb1.x, bb1.y, bb1.z, bb1.w};
  #pragma unroll
  for (int i = 0; i < 8; ++i) {
    int gr = row0 + ty * 8 + i;
    if (gr >= NN) continue;
    float o[8];
    #pragma unroll
    for (int j = 0; j < 8; ++j) {
      float v = acc[i][j] + bB[j];
      o[j] = (v >= 0.f) ? v : SLOPE * v;
    }
    *(float4*)(out + (size_t)gr * DD + tx * 4)      = make_float4(o[0], o[1], o[2], o[3]);
    *(float4*)(out + (size_t)gr * DD + 64 + tx * 4) = make_float4(o[4], o[5], o[6], o[7]);
  }
}

extern "C" void kernel_launch(void* const* d_in, const int* in_sizes, int n_in,
                              void* d_out, int out_size, void* d_ws, size_t ws_size,
                              hipStream_t stream) {
  const float* x     = (const float*)d_in[0];
  const int*   ei    = (const int*)d_in[1];
  const float* W     = (const float*)d_in[2];
  const float* b     = (const float*)d_in[3];
  const float* gamma = (const float*)d_in[4];
  const float* beta  = (const float*)d_in[5];
  const float* mean  = (const float*)d_in[6];
  const float* var   = (const float*)d_in[7];
  const float* rsW   = (const float*)d_in[8];
  const float* rsb   = (const float*)d_in[9];
  float* out = (float*)d_out;
  const int* src = ei;         // edge_index[0]
  const int* dst = ei + EE;    // edge_index[1]

  // workspace carve-up (all 4B types; base alignment from harness)
  float* z      = (float*)d_ws;
  float* y      = z + (size_t)NN * DD;
  int*   cnt    = (int*)(y + (size_t)NN * DD);
  float* dinv   = (float*)(cnt + NN);
  int*   rp     = (int*)(dinv + NN);
  int*   cursor = rp + NN + 1;
  int*   csr    = cursor + NN;
  int*   bsum   = csr + EE;
  float* bias2  = (float*)(bsum + 1024);

  const int EB = (EE + 255) / 256;   // 6250
  const int NB = (NN + 255) / 256;   // 391

  k_bias<<<1, 128, 0, stream>>>(b, rsb, bias2);
  k_norm_bn<<<NN / 4, 256, 0, stream>>>(x, gamma, beta, mean, var, z);
  k_zero<<<NB, 256, 0, stream>>>(cnt, NN);
  k_zero<<<NB, 256, 0, stream>>>(cursor, NN);
  k_count<<<EB, 256, 0, stream>>>(dst, cnt);
  k_dinv<<<NB, 256, 0, stream>>>(cnt, dinv);
  k_scan1<<<NB, 256, 0, stream>>>(cnt, rp, bsum, NN);
  k_scan2<<<1, 512, 0, stream>>>(bsum, NB);
  k_scan3<<<NB, 256, 0, stream>>>(rp, bsum, NN);
  k_scatter<<<EB, 256, 0, stream>>>(src, dst, rp, cursor, csr);
  k_aggregate<<<NN / 4, 256, 0, stream>>>(z, rp, csr, dinv, y);
  k_gemm<<<(NN + 127) / 128, 256, 0, stream>>>(y, z, W, rsW, bias2, out);
}